// Round 3
// baseline (706.899 us; speedup 1.0000x reference)
//
#include <hip/hip_runtime.h>

#define NN 128
#define ME 32
#define DI 64
#define NZ 96
#define ROWD 130
#define MAXIT 5000

// ---- LDS layout (double offsets). R: [0, 16640). Total 20040 dbl = 160320 B <= 163840.
#define OFF_UN 16640
#define ROWB  (OFF_UN)           // [2][128] sweep row-k buffer (phase 2)
#define COLB  (OFF_UN + 256)     // [2][128] sweep col-k buffer (phase 2)
// loop window (wave-4 obj offload design):
#define PPK   (OFF_UN)           // [2][4][64] packed (lo,hi) f32 partials in b64 slots
#define ZEXL  (OFF_UN + 512)     // [2][64] f64 z_lo publish (w0 -> wave4 tv)
#define ZEXH  (OFF_UN + 640)     // [2][32] f64 z_hi publish (w3 -> wave4 tv)
#define TVX   (OFF_UN + 704)     // [2][64] f64 per-lane tv terms (wave4 internal)
#define TV16  (OFF_UN + 832)     // [2][16] f64 stage-A sums (wave4 internal)
#define FLG   (OFF_UN + 864)     // [2] convergence flag (double 0/1)
#define YBUF  (OFF_UN)           // [128][12] Y block (stage 2; dead before loop)
#define KBUF  (OFF_UN + 1536)    // [12][96] K cols (stage 2; dead before loop)
#define CPART (OFF_UN + 1024)    // [2][128] (stage 3a)
#define VP    (OFF_UN + 1280)    // [4][128] (stage 3b)
#define BASEV (OFF_UN + 1792)    // [96] (persists through loop)
#define QBV   (OFF_UN + 1888)    // [96] (persists through loop)
#define FPART (OFF_UN + 1024)    // [2][128] (final)
#define RHSV  (OFF_UN + 1280)    // [128] (final)
#define XPART (OFF_UN + 1408)    // [2][128] (final)
#define CB    (OFF_UN + 2688)    // [128] c
#define QBUF  (OFF_UN + 2816)    // [128] q
#define V1    (OFF_UN + 2944)    // [128] Rc
#define V2    (OFF_UN + 3072)    // [128] Rq
#define HB    (OFF_UN + 3200)    // [64]
#define BB    (OFF_UN + 3264)    // [32]
#define CST   (OFF_UN + 3296)    // [8]: 0=u.c 1=q.u
#define ZBF   (OFF_UN + 3304)    // [96] z publish (final)
#define LDS_DBL (OFF_UN + 3400)  // 20040

typedef __attribute__((ext_vector_type(2))) float f32x2;

// f32 SGPR broadcast. CONTRACT: source computed by all lanes of the wave.
__device__ __forceinline__ float rlf(float v, int lane) {
  return __uint_as_float((unsigned)__builtin_amdgcn_readlane((int)__float_as_uint(v), lane));
}
__device__ __forceinline__ f32x2 fma2(f32x2 a, f32x2 b, f32x2 c) {
  return __builtin_elementwise_fma(a, b, c);   // v_pk_fma_f32
}

// matvec step: 2 pairs (4 cols) with broadcast lanes L0..L0+3 of ZS
#define MV2(PA, ZS, L0) {                                                  \
    f32x2 z0 = { rlf(ZS, L0), rlf(ZS, (L0)+1) };                           \
    A0 = fma2(Kp[PA], z0, A0); B0 = fma2(Kp2[PA], z0, B0);                 \
    f32x2 z1 = { rlf(ZS, (L0)+2), rlf(ZS, (L0)+3) };                       \
    A1 = fma2(Kp[(PA)+1], z1, A1); B1 = fma2(Kp2[(PA)+1], z1, B1); }

__global__ __launch_bounds__(320, 1) void altdiff_kernel(
    const float* __restrict__ Qg, const float* __restrict__ qg,
    const float* __restrict__ Gg, const float* __restrict__ hg,
    const float* __restrict__ Ag, const float* __restrict__ bg,
    float* __restrict__ out)
{
  extern __shared__ double ldsd[];

  const int bidx = blockIdx.x;
  const int tid  = threadIdx.x;
  const int w    = tid >> 6;     // wave 0..4 (wave 4 = objective wave)
  const int l    = tid & 63;     // lane
  const int lm   = l & 31;
  const int ia   = tid & 127;    // 128-split index (setup only, tid<256)
  const int hh   = tid >> 7;     // 0..1 for tid<256 (setup only)

  const float* Qb = Qg + (size_t)bidx * NN * NN;
  const float* Ab = Ag + (size_t)bidx * ME * NN;
  const float* Gb = Gg + (size_t)bidx * DI * NN;
  const float* qb = qg + (size_t)bidx * NN;
  const float* hb = hg + (size_t)bidx * DI;
  const float* bv = bg + (size_t)bidx * ME;

  // stage h, b, q (f64) — guard: wave 4 must not write out of range
  if (tid < DI) ldsd[HB + tid] = (double)hb[tid];
  else if (tid < DI + ME) ldsd[BB + tid - DI] = (double)bv[tid - DI];
  if (tid >= 128 && tid < 256) ldsd[QBUF + tid - 128] = (double)qb[tid - 128];

  const int r = tid >> 4, c = tid & 15;   // 8x8 register tile (valid for tid<256)
  double acc[8][8];                       // ALL indices compile-time constant (no scratch)

  // ---------------- Phase 1: M = Q + A^T A + G^T G (f64) -> registers ----------------
  if (tid < 256) {
    const float4* Q4 = (const float4*)Qb;
#pragma unroll
    for (int rr = 0; rr < 8; ++rr) {
      float4 q0 = Q4[((8*r+rr) << 5) + 2*c];
      float4 q1 = Q4[((8*r+rr) << 5) + 2*c + 1];
      acc[rr][0]=(double)q0.x; acc[rr][1]=(double)q0.y; acc[rr][2]=(double)q0.z; acc[rr][3]=(double)q0.w;
      acc[rr][4]=(double)q1.x; acc[rr][5]=(double)q1.y; acc[rr][6]=(double)q1.z; acc[rr][7]=(double)q1.w;
    }
    const float4* A4 = (const float4*)Ab;
    for (int m = 0; m < ME; ++m) {
      float4 u0 = A4[(m << 5) + 2*r], u1 = A4[(m << 5) + 2*r + 1];
      float4 v0 = A4[(m << 5) + 2*c], v1 = A4[(m << 5) + 2*c + 1];
      double uu[8] = {(double)u0.x,(double)u0.y,(double)u0.z,(double)u0.w,
                      (double)u1.x,(double)u1.y,(double)u1.z,(double)u1.w};
      double vv[8] = {(double)v0.x,(double)v0.y,(double)v0.z,(double)v0.w,
                      (double)v1.x,(double)v1.y,(double)v1.z,(double)v1.w};
#pragma unroll
      for (int rr = 0; rr < 8; ++rr)
#pragma unroll
        for (int cc = 0; cc < 8; ++cc)
          acc[rr][cc] = fma(uu[rr], vv[cc], acc[rr][cc]);
    }
    const float4* G4 = (const float4*)Gb;
    for (int d = 0; d < DI; ++d) {
      float4 u0 = G4[(d << 5) + 2*r], u1 = G4[(d << 5) + 2*r + 1];
      float4 v0 = G4[(d << 5) + 2*c], v1 = G4[(d << 5) + 2*c + 1];
      double uu[8] = {(double)u0.x,(double)u0.y,(double)u0.z,(double)u0.w,
                      (double)u1.x,(double)u1.y,(double)u1.z,(double)u1.w};
      double vv[8] = {(double)v0.x,(double)v0.y,(double)v0.z,(double)v0.w,
                      (double)v1.x,(double)v1.y,(double)v1.z,(double)v1.w};
#pragma unroll
      for (int rr = 0; rr < 8; ++rr)
#pragma unroll
        for (int cc = 0; cc < 8; ++cc)
          acc[rr][cc] = fma(uu[rr], vv[cc], acc[rr][cc]);
    }
  }

  // ---------------- Phase 2: register-tile sweep, 1 barrier/pivot, double-buffered ----------
  if (tid < 256) {
    if (r == 0) {
#pragma unroll
      for (int cc = 0; cc < 8; ++cc) ldsd[ROWB + 8*c + cc] = acc[0][cc];
    }
    if (c == 0) {
#pragma unroll
      for (int rr = 0; rr < 8; ++rr) ldsd[COLB + 8*r + rr] = acc[rr][0];
    }
  }
  __syncthreads();
  for (int k = 0; k < NN; ++k) {
    if (tid < 256) {
      const int pb = (k & 1) << 7;
      const int krt = k >> 3, kcl = k & 7;
      double rowk[8], colv[8];
#pragma unroll
      for (int cc = 0; cc < 8; ++cc) rowk[cc] = ldsd[ROWB + pb + 8*c + cc];
#pragma unroll
      for (int rr = 0; rr < 8; ++rr) colv[rr] = ldsd[COLB + pb + 8*r + rr];
      const double dkk  = ldsd[ROWB + pb + k];     // same-address broadcast
      const double rcpd = 1.0 / dkk;               // pivots >= 1 (M >= I)
      double rdv[8];
#pragma unroll
      for (int cc = 0; cc < 8; ++cc) rdv[cc] = rowk[cc] * rcpd;
      const bool pivR = (r == krt), pivC = (c == krt);
#pragma unroll
      for (int rr = 0; rr < 8; ++rr) {
        const double cv = colv[rr] * rcpd;
        const bool pr = pivR && (rr == kcl);
#pragma unroll
        for (int cc = 0; cc < 8; ++cc) {
          double gen = fma(-cv, rowk[cc], acc[rr][cc]);
          acc[rr][cc] = pr ? rdv[cc] : gen;
        }
      }
      if (pivC) {
#pragma unroll
        for (int cc = 0; cc < 8; ++cc) if (cc == kcl) {
#pragma unroll
          for (int rr = 0; rr < 8; ++rr) {
            const bool pr2 = pivR && (rr == kcl);
            acc[rr][cc] = pr2 ? -rcpd : colv[rr] * rcpd;
          }
        }
      }
      if (k < NN - 1) {
        const int pb2 = ((k + 1) & 1) << 7;
        const int krt2 = (k + 1) >> 3, kcl2 = (k + 1) & 7;
        if (r == krt2) {
#pragma unroll
          for (int rr = 0; rr < 8; ++rr) if (rr == kcl2) {
#pragma unroll
            for (int cc = 0; cc < 8; ++cc) ldsd[ROWB + pb2 + 8*c + cc] = acc[rr][cc];
          }
        }
        if (c == krt2) {
#pragma unroll
          for (int cc = 0; cc < 8; ++cc) if (cc == kcl2) {
#pragma unroll
            for (int rr = 0; rr < 8; ++rr) ldsd[COLB + pb2 + 8*r + rr] = acc[rr][cc];
          }
        }
      }
    }
    __syncthreads();
  }
  if (tid < 256) {
#pragma unroll
    for (int rr = 0; rr < 8; ++rr) {
      double2* dst = (double2*)(ldsd + (8*r+rr)*ROWD + 8*c);
#pragma unroll
      for (int t = 0; t < 4; ++t) dst[t] = make_double2(acc[rr][2*t], acc[rr][2*t+1]);
    }
  }
  __syncthreads();

  // ---------------- Stage 2: K = B (R B^T) in 8 blocks of 12 cols --------
  // Wave w (0..3) holds cols 24w..24w+23 as f32x2 pairs. Wave 4 holds nothing.
  f32x2 Kp[12], Kp2[12];
  for (int blk = 0; blk < 8; ++blk) {
    if (tid < 256) {
      const float* gp[6];
#pragma unroll
      for (int jj = 0; jj < 6; ++jj) {
        int it = 12*blk + 6*hh + jj;
        gp[jj] = (it < DI) ? (Gb + it*NN) : (Ab + (it - DI)*NN);
      }
      double a2[6] = {0,0,0,0,0,0};
#pragma unroll 4
      for (int t = 0; t < NN; ++t) {
        double rv = ldsd[t*ROWD + ia];
#pragma unroll
        for (int jj = 0; jj < 6; ++jj)
          a2[jj] = fma(rv, (double)gp[jj][t], a2[jj]);
      }
      double2* yst = (double2*)(ldsd + YBUF + ia*12 + 6*hh);
#pragma unroll
      for (int p = 0; p < 3; ++p) yst[p] = make_double2(a2[2*p], a2[2*p+1]);
    }
    __syncthreads();
    if (tid < 256) {
      const int r2 = (ia < NZ) ? ia : 0;
      const float* brow = (r2 < DI) ? (Gb + r2*NN) : (Ab + (r2 - DI)*NN);
      double a2[6] = {0,0,0,0,0,0};
#pragma unroll 4
      for (int t = 0; t < NN; ++t) {
        double bvv = (double)brow[t];
        const double2* yr = (const double2*)(ldsd + YBUF + t*12 + 6*hh);
        double2 y0 = yr[0], y1 = yr[1], y2 = yr[2];
        a2[0] = fma(bvv, y0.x, a2[0]); a2[1] = fma(bvv, y0.y, a2[1]);
        a2[2] = fma(bvv, y1.x, a2[2]); a2[3] = fma(bvv, y1.y, a2[3]);
        a2[4] = fma(bvv, y2.x, a2[4]); a2[5] = fma(bvv, y2.y, a2[5]);
      }
      if (ia < NZ) {
#pragma unroll
        for (int jj = 0; jj < 6; ++jj) ldsd[KBUF + (6*hh + jj)*NZ + ia] = a2[jj];
      }
    }
    __syncthreads();
    if (w == (blk >> 1)) {          // CONSTANT-index copies (r5 spill fix); wave4 never matches
      if ((blk & 1) == 0) {
#pragma unroll
        for (int p = 0; p < 6; ++p) {
          Kp [p].x = (float)ldsd[KBUF + (2*p  )*NZ + l];
          Kp [p].y = (float)ldsd[KBUF + (2*p+1)*NZ + l];
          Kp2[p].x = (float)ldsd[KBUF + (2*p  )*NZ + 64 + lm];
          Kp2[p].y = (float)ldsd[KBUF + (2*p+1)*NZ + 64 + lm];
        }
      } else {
#pragma unroll
        for (int p = 0; p < 6; ++p) {
          Kp [6+p].x = (float)ldsd[KBUF + (2*p  )*NZ + l];
          Kp [6+p].y = (float)ldsd[KBUF + (2*p+1)*NZ + l];
          Kp2[6+p].x = (float)ldsd[KBUF + (2*p  )*NZ + 64 + lm];
          Kp2[6+p].y = (float)ldsd[KBUF + (2*p+1)*NZ + 64 + lm];
        }
      }
    }
    __syncthreads();
  }

  // ---------------- Stage 3a: c = q - G^T h - A^T b ----------------
  if (tid < 256) {
    double s = 0;
#pragma unroll 8
    for (int jc = 0; jc < 48; ++jc) {
      int j = 48*hh + jc;
      double coef = (j < DI) ? ldsd[HB + j] : ldsd[BB + j - DI];
      const float* src = (j < DI) ? (Gb + j*NN) : (Ab + (j - DI)*NN);
      s = fma(-(double)src[ia], coef, s);
    }
    ldsd[CPART + hh*128 + ia] = s;
  }
  __syncthreads();
  if (tid < NN) ldsd[CB + tid] = ldsd[QBUF + tid] + ldsd[CPART + tid] + ldsd[CPART + 128 + tid];
  __syncthreads();

  // ---------------- Stage 3b: v1 = R c, v2 = R q ----------------
  if (tid < 256) {
    double a = 0, b2 = 0;
#pragma unroll 4
    for (int tt = 0; tt < 64; ++tt) {
      int t = 64*hh + tt;
      double rv = ldsd[t*ROWD + ia];
      a  = fma(rv, ldsd[CB + t], a);
      b2 = fma(rv, ldsd[QBUF + t], b2);
    }
    ldsd[VP + hh*128 + ia] = a;
    ldsd[VP + 256 + hh*128 + ia] = b2;
  }
  __syncthreads();
  if (tid < NN) {
    ldsd[V1 + tid] = ldsd[VP + tid] + ldsd[VP + 128 + tid];
    ldsd[V2 + tid] = ldsd[VP + 256 + tid] + ldsd[VP + 384 + tid];
  }
  __syncthreads();

  // ---------------- Stage 3c: base = B v1, qB = B v2, scalars ----------------
  if (tid < 256) {
    const int r2 = (ia < NZ) ? ia : 0;
    const float* brow = (r2 < DI) ? (Gb + r2*NN) : (Ab + (r2 - DI)*NN);
    const int voff = hh ? V2 : V1;
    double s = 0;
#pragma unroll 4
    for (int t = 0; t < NN; ++t) s = fma((double)brow[t], ldsd[voff + t], s);
    if (ia < NZ) ldsd[(hh ? QBV : BASEV) + ia] = s;
  }
  if (w == 0) {
    double pc = ldsd[V1+l]*ldsd[CB+l]   + ldsd[V1+64+l]*ldsd[CB+64+l];
    double pq = ldsd[V1+l]*ldsd[QBUF+l] + ldsd[V1+64+l]*ldsd[QBUF+64+l];
#pragma unroll
    for (int off = 32; off >= 1; off >>= 1) { pc += __shfl_xor(pc, off); pq += __shfl_xor(pq, off); }
    if (l == 0) { ldsd[CST] = pc; ldsd[CST+1] = pq; }
  }
  __syncthreads();

  // ---------------- Loop setup ----------------
  // Matvec waves w0..w3: 24 cols each (w0: lo 0-23, w1: lo 24-47, w2: lo 48-63 + hi 0-7,
  //   w3: hi 8-31). w0 also: lo ring + z_lo publish. w3: hi ring + z_hi publish.
  // Wave 4: the ENTIRE objective pipeline (tv -> stageA -> stageB -> flag), timing
  //   identical to the previous (passing) kernel: flag for body k stored at body k+2,
  //   consumed at body k+3 => t* = bb-3, publish ring zC = z_top(t*).
  const double baseA = ldsd[BASEV + l];
  const double baseB = ldsd[BASEV + 64 + lm];
  const double qvA   = ldsd[QBV + l];
  const double qvB   = ldsd[QBV + 64 + lm];
  const double hb2   = ldsd[HB + l] - baseA;       // h - baseA
  const double bb2   = baseB - ldsd[BB + lm];      // baseB - b
  const double S_uc  = ldsd[CST], S_qu = ldsd[CST + 1];
  double hnb = hb2, lb = bb2;                      // nu = 0, lam = 0 folded
  double zlo = 0.0, zhi = 0.0;
  double zAlo = 0.0, zAhi = 0.0, zBlo = 0.0, zBhi = 0.0, zClo = 0.0, zChi = 0.0;
  double res_prev = 1000.0, res_cur = -100.0;      // wave-4 obj recurrence

  // prologue: zero P buf0 (base folded into hb2/bb2); z(-1)=0 into ZEX buf1; flags 0
  {
    if (w < 4) ((float2*)&ldsd[PPK + (w << 6) + l])[0] = make_float2(0.f, 0.f);
    if (w == 0) ldsd[ZEXL + 64 + l] = 0.0;
    if (w == 3 && l < 32) ldsd[ZEXH + 32 + l] = 0.0;
    if (tid == 0) { ldsd[FLG] = 0.0; ldsd[FLG + 1] = 0.0; }
  }

  // ---------------- ADMM loop: 1 barrier/body ----------------
  for (int it = 0; it < MAXIT + 3; ++it) {
    __syncthreads();
    const int buf = it & 1, nbuf = buf ^ 1;
    const int bprev = nbuf;                 // (it-1)&1
    const double fl = ldsd[FLG + bprev];    // flag stored body it-1 = decision for obj_{it-3}

    if (w < 4) {
      // packed partial reads: 4 b64 slots -> (lo,hi) f32 pairs, lane-consecutive
      const float2* pb = (const float2*)(ldsd + PPK + buf*256);
      float2 v0 = pb[l], v1 = pb[64 + l], v2 = pb[128 + l], v3 = pb[192 + l];
      double t = 0.0, lamn = 0.0;
      float zflo = 0.f, zfhi = 0.f;
      if (w != 3) {                 // lo chain (waves 0,1,2): z_lo = |t|
        float s = (v0.x + v1.x) + (v2.x + v3.x);
        t = hnb - (double)s;
        zflo = (float)fabs(t);
      }
      if (w >= 2) {                 // hi chain (waves 2,3): z_hi = lam'
        float sh = (v0.y + v1.y) + (v2.y + v3.y);
        lamn = lb + (double)sh;
        zfhi = (float)lamn;
      }
      if (it >= 3 && fl != 0.0) break;
      // ring shifts (zA = z entering THIS body)
      if (w == 0) { zClo = zBlo; zBlo = zAlo; zAlo = zlo; }
      if (w == 3) { zChi = zBhi; zBhi = zAhi; zAhi = zhi; }
      if (it < MAXIT) {
        if (w == 0) { zlo = fabs(t); ldsd[ZEXL + buf*64 + l] = zlo; }
        if (w != 3) hnb = hb2 + fmin(t, 0.0);          // = hb2 - relu(-t)
        if (w == 3) { zhi = lamn; if (l < 32) ldsd[ZEXH + buf*32 + l] = lamn; }
        if (w >= 2) lb = lamn + bb2;
        // matvec burst: 24 cols per wave
        f32x2 A0 = {0.f, 0.f}, A1 = A0, B0 = A0, B1 = A0;
        if (w == 0) {
          MV2(0, zflo, 0)  MV2(2, zflo, 4)  MV2(4, zflo, 8)
          MV2(6, zflo, 12) MV2(8, zflo, 16) MV2(10, zflo, 20)
        } else if (w == 1) {
          MV2(0, zflo, 24) MV2(2, zflo, 28) MV2(4, zflo, 32)
          MV2(6, zflo, 36) MV2(8, zflo, 40) MV2(10, zflo, 44)
        } else if (w == 2) {
          MV2(0, zflo, 48) MV2(2, zflo, 52) MV2(4, zflo, 56) MV2(6, zflo, 60)
          MV2(8, zfhi, 0)  MV2(10, zfhi, 4)
        } else {
          MV2(0, zfhi, 8)  MV2(2, zfhi, 12) MV2(4, zfhi, 16)
          MV2(6, zfhi, 20) MV2(8, zfhi, 24) MV2(10, zfhi, 28)
        }
        f32x2 As = A0 + A1, Bs = B0 + B1;     // v_pk_add_f32
        ((float2*)&ldsd[PPK + nbuf*256 + (w << 6) + l])[0] =
            make_float2(As.x + As.y, Bs.x + Bs.y);
      }
    } else {
      // ---------------- wave 4: objective pipeline ----------------
      // loads first (unconditional; garbage pre-warm harmless, stores are guarded)
      const float2* pb = (const float2*)(ldsd + PPK + buf*256);
      float2 v0 = pb[l], v1 = pb[64 + l], v2 = pb[128 + l], v3 = pb[192 + l];
      const double zAl = ldsd[ZEXL + bprev*64 + l];    // z_top(it) = z(it-1)
      const double zAh = ldsd[ZEXH + bprev*32 + lm];
      const int g = l & 15;
      const double* tq = ldsd + TVX + bprev*64;        // tv(it-1), stride-16 quartet
      double a0 = tq[g], a1 = tq[g + 16], a2 = tq[g + 32], a3 = tq[g + 48];
      double t1v[16];
      const double2* tp = (const double2*)(ldsd + TV16 + bprev*16);  // sums of tv(it-2)
#pragma unroll
      for (int u = 0; u < 8; ++u) { double2 vv = tp[u]; t1v[2*u] = vv.x; t1v[2*u+1] = vv.y; }
      if (it >= 3 && fl != 0.0) break;
      // stage tv (pipeline it): per-lane terms from y(it) and zA(it)
      if (it < MAXIT) {
        float slo_f = (v0.x + v1.x) + (v2.x + v3.x);
        float shi_f = (v0.y + v1.y) + (v2.y + v3.y);
        double yf  = (double)slo_f + baseA;
        double tvl = fma(qvA, zAl, -0.5*(zAl*(baseA + yf) + yf*yf));
        double yfB = (double)shi_f + baseB;
        double tvh = fma(qvB, zAh, -0.5*(zAh*(baseB + yfB) + yfB*yfB));
        ldsd[TVX + buf*64 + l] = tvl + ((l < 32) ? tvh : 0.0);
      }
      // stage A (pipeline it-1): quartet partial sums -> 16 values
      if (l < 16 && it >= 1 && it <= MAXIT)
        ldsd[TV16 + buf*16 + l] = (a0 + a1) + (a2 + a3);
      // stage B (pipeline it-2): obj -> rel criterion -> flag
      if (it >= 2 && it <= MAXIT + 1) {
        double s1 = ((t1v[0] + t1v[1]) + (t1v[2] + t1v[3])) + ((t1v[4] + t1v[5]) + (t1v[6] + t1v[7]));
        double s2 = ((t1v[8] + t1v[9]) + (t1v[10] + t1v[11])) + ((t1v[12] + t1v[13]) + (t1v[14] + t1v[15]));
        double obj = (s1 + s2) - 0.5*S_uc + S_qu;
        res_prev = res_cur; res_cur = obj;
        if (l == 0)
          ldsd[FLG + buf] = (fabs(res_cur - res_prev) <= 1e-5 * fabs(res_prev)) ? 1.0 : 0.0;
      }
    }
  }

  // ---------------- Final: publish z (rings: zC = top-of-stopping-body) -> LDS ------
  if (w == 0) ldsd[ZBF + l] = zClo;
  if (w == 3 && l < 32) ldsd[ZBF + 64 + l] = zChi;
  __syncthreads();
  // x = R (c + B^T z); z read via broadcast LDS loads
  if (tid < 256) {
    double s = 0;
#pragma unroll 8
    for (int jc = 0; jc < 48; ++jc) {
      int j = 48*hh + jc;
      double zj = ldsd[ZBF + j];
      const float* src = (j < DI) ? (Gb + j*NN) : (Ab + (j - DI)*NN);
      s = fma((double)src[ia], zj, s);
    }
    ldsd[FPART + hh*128 + ia] = s;
  }
  __syncthreads();
  if (tid < NN) ldsd[RHSV + tid] = ldsd[CB + tid] + ldsd[FPART + tid] + ldsd[FPART + 128 + tid];
  __syncthreads();
  if (tid < 256) {
    double s = 0;
#pragma unroll 4
    for (int tt = 0; tt < 64; ++tt) {
      int t = 64*hh + tt;
      s = fma(ldsd[t*ROWD + ia], ldsd[RHSV + t], s);   // R[t][ia] = R[ia][t]
    }
    ldsd[XPART + hh*128 + ia] = s;
  }
  __syncthreads();
  if (tid < NN)
    out[(size_t)bidx * NN + tid] = (float)(ldsd[XPART + tid] + ldsd[XPART + 128 + tid]);
}

extern "C" void kernel_launch(void* const* d_in, const int* in_sizes, int n_in,
                              void* d_out, int out_size, void* d_ws, size_t ws_size,
                              hipStream_t stream) {
  (void)in_sizes; (void)n_in; (void)out_size; (void)d_ws; (void)ws_size;
  const float* Q = (const float*)d_in[0];
  const float* q = (const float*)d_in[1];
  const float* G = (const float*)d_in[2];
  const float* h = (const float*)d_in[3];
  const float* A = (const float*)d_in[4];
  const float* b = (const float*)d_in[5];
  float* out = (float*)d_out;
  const size_t lds_bytes = (size_t)LDS_DBL * sizeof(double);  // 160320
  altdiff_kernel<<<dim3(64), dim3(320), lds_bytes, stream>>>(Q, q, G, h, A, b, out);
}

// Round 4
// 630.963 us; speedup vs baseline: 1.1203x; 1.1203x over previous
//
#include <hip/hip_runtime.h>

#define NN 128
#define ME 32
#define DI 64
#define NZ 96
#define ROWD 130
#define MAXIT 5000

// ---- LDS layout (double offsets). R: [0, 16640). Total 20040 dbl = 160320 B <= 163840.
#define OFF_UN 16640
#define ROWB  (OFF_UN)           // [2][128] sweep row-k buffer (phase 2)
#define COLB  (OFF_UN + 256)     // [2][128] sweep col-k buffer (phase 2)
// loop window (2-slot exchange + split obj pipeline):
#define PPK   (OFF_UN)           // [2][2][64] packed (lo,hi) f32 partials in b64 slots
#define ZEXL  (OFF_UN + 256)     // [2][64] f64 z_lo publish (w0 -> w2 tv)
#define ZEXH  (OFF_UN + 384)     // [2][32] f64 z_hi publish (w1 -> w2 tv)
#define TVX   (OFF_UN + 448)     // [2][64] f64 per-lane tv terms (w2 internal)
#define TV16  (OFF_UN + 576)     // [2][16] f64 stage-A sums (w2 -> w3)
#define FLG   (OFF_UN + 608)     // [2] convergence flag (double 0/1)
#define YBUF  (OFF_UN)           // [128][12] Y block (stage 2; dead before loop)
#define KBUF  (OFF_UN + 1536)    // [12][96] K cols (stage 2; dead before loop)
#define CPART (OFF_UN + 1024)    // [2][128] (stage 3a)
#define VP    (OFF_UN + 1280)    // [4][128] (stage 3b)
#define BASEV (OFF_UN + 1792)    // [96] (persists through loop)
#define QBV   (OFF_UN + 1888)    // [96] (persists through loop)
#define FPART (OFF_UN + 1024)    // [2][128] (final)
#define RHSV  (OFF_UN + 1280)    // [128] (final)
#define XPART (OFF_UN + 1408)    // [2][128] (final)
#define CB    (OFF_UN + 2688)    // [128] c
#define QBUF  (OFF_UN + 2816)    // [128] q
#define V1    (OFF_UN + 2944)    // [128] Rc
#define V2    (OFF_UN + 3072)    // [128] Rq
#define HB    (OFF_UN + 3200)    // [64]
#define BB    (OFF_UN + 3264)    // [32]
#define CST   (OFF_UN + 3296)    // [8]: 0=u.c 1=q.u
#define ZBF   (OFF_UN + 3304)    // [96] z publish (final)
#define LDS_DBL (OFF_UN + 3400)  // 20040

typedef __attribute__((ext_vector_type(2))) float f32x2;

// f32 SGPR broadcast. CONTRACT: source computed by all lanes of the wave.
__device__ __forceinline__ float rlf(float v, int lane) {
  return __uint_as_float((unsigned)__builtin_amdgcn_readlane((int)__float_as_uint(v), lane));
}
__device__ __forceinline__ f32x2 fma2(f32x2 a, f32x2 b, f32x2 c) {
  return __builtin_elementwise_fma(a, b, c);   // v_pk_fma_f32
}

// matvec step: 2 pairs (4 cols) with broadcast lanes L0..L0+3 of ZS
#define MV2(PA, ZS, L0) {                                                  \
    f32x2 z0 = { rlf(ZS, L0), rlf(ZS, (L0)+1) };                           \
    A0 = fma2(Kp[PA], z0, A0); B0 = fma2(Kp2[PA], z0, B0);                 \
    f32x2 z1 = { rlf(ZS, (L0)+2), rlf(ZS, (L0)+3) };                       \
    A1 = fma2(Kp[(PA)+1], z1, A1); B1 = fma2(Kp2[(PA)+1], z1, B1); }

// copy 12 KBUF cols (0..11 of current blk) into local pairs LB..LB+5
#define CPY12(LB)                                                          \
  _Pragma("unroll") for (int p = 0; p < 6; ++p) {                          \
    Kp [(LB)+p].x = (float)ldsd[KBUF + (2*p  )*NZ + l];                    \
    Kp [(LB)+p].y = (float)ldsd[KBUF + (2*p+1)*NZ + l];                    \
    Kp2[(LB)+p].x = (float)ldsd[KBUF + (2*p  )*NZ + 64 + lm];              \
    Kp2[(LB)+p].y = (float)ldsd[KBUF + (2*p+1)*NZ + 64 + lm];              \
  }

__global__ __launch_bounds__(256, 1) void altdiff_kernel(
    const float* __restrict__ Qg, const float* __restrict__ qg,
    const float* __restrict__ Gg, const float* __restrict__ hg,
    const float* __restrict__ Ag, const float* __restrict__ bg,
    float* __restrict__ out)
{
  extern __shared__ double ldsd[];

  const int bidx = blockIdx.x;
  const int tid  = threadIdx.x;
  const int w    = tid >> 6;     // wave 0..3
  const int l    = tid & 63;     // lane
  const int lm   = l & 31;
  const int ia   = tid & 127;    // 128-split index
  const int hh   = tid >> 7;     // 0..1 (wave-uniform)

  const float* Qb = Qg + (size_t)bidx * NN * NN;
  const float* Ab = Ag + (size_t)bidx * ME * NN;
  const float* Gb = Gg + (size_t)bidx * DI * NN;
  const float* qb = qg + (size_t)bidx * NN;
  const float* hb = hg + (size_t)bidx * DI;
  const float* bv = bg + (size_t)bidx * ME;

  // stage h, b, q (f64)
  if (tid < DI) ldsd[HB + tid] = (double)hb[tid];
  else if (tid < DI + ME) ldsd[BB + tid - DI] = (double)bv[tid - DI];
  if (tid >= 128) ldsd[QBUF + tid - 128] = (double)qb[tid - 128];

  const int r = tid >> 4, c = tid & 15;   // 8x8 register tile at rows 8r.., cols 8c..
  double acc[8][8];                       // ALL indices compile-time constant (no scratch)

  // ---------------- Phase 1: M = Q + A^T A + G^T G (f64) -> registers ----------------
  {
    const float4* Q4 = (const float4*)Qb;
#pragma unroll
    for (int rr = 0; rr < 8; ++rr) {
      float4 q0 = Q4[((8*r+rr) << 5) + 2*c];
      float4 q1 = Q4[((8*r+rr) << 5) + 2*c + 1];
      acc[rr][0]=(double)q0.x; acc[rr][1]=(double)q0.y; acc[rr][2]=(double)q0.z; acc[rr][3]=(double)q0.w;
      acc[rr][4]=(double)q1.x; acc[rr][5]=(double)q1.y; acc[rr][6]=(double)q1.z; acc[rr][7]=(double)q1.w;
    }
    const float4* A4 = (const float4*)Ab;
    for (int m = 0; m < ME; ++m) {
      float4 u0 = A4[(m << 5) + 2*r], u1 = A4[(m << 5) + 2*r + 1];
      float4 v0 = A4[(m << 5) + 2*c], v1 = A4[(m << 5) + 2*c + 1];
      double uu[8] = {(double)u0.x,(double)u0.y,(double)u0.z,(double)u0.w,
                      (double)u1.x,(double)u1.y,(double)u1.z,(double)u1.w};
      double vv[8] = {(double)v0.x,(double)v0.y,(double)v0.z,(double)v0.w,
                      (double)v1.x,(double)v1.y,(double)v1.z,(double)v1.w};
#pragma unroll
      for (int rr = 0; rr < 8; ++rr)
#pragma unroll
        for (int cc = 0; cc < 8; ++cc)
          acc[rr][cc] = fma(uu[rr], vv[cc], acc[rr][cc]);
    }
    const float4* G4 = (const float4*)Gb;
    for (int d = 0; d < DI; ++d) {
      float4 u0 = G4[(d << 5) + 2*r], u1 = G4[(d << 5) + 2*r + 1];
      float4 v0 = G4[(d << 5) + 2*c], v1 = G4[(d << 5) + 2*c + 1];
      double uu[8] = {(double)u0.x,(double)u0.y,(double)u0.z,(double)u0.w,
                      (double)u1.x,(double)u1.y,(double)u1.z,(double)u1.w};
      double vv[8] = {(double)v0.x,(double)v0.y,(double)v0.z,(double)v0.w,
                      (double)v1.x,(double)v1.y,(double)v1.z,(double)v1.w};
#pragma unroll
      for (int rr = 0; rr < 8; ++rr)
#pragma unroll
        for (int cc = 0; cc < 8; ++cc)
          acc[rr][cc] = fma(uu[rr], vv[cc], acc[rr][cc]);
    }
  }

  // ---------------- Phase 2: register-tile sweep, 1 barrier/pivot, double-buffered ----------
  {
    if (r == 0) {
#pragma unroll
      for (int cc = 0; cc < 8; ++cc) ldsd[ROWB + 8*c + cc] = acc[0][cc];
    }
    if (c == 0) {
#pragma unroll
      for (int rr = 0; rr < 8; ++rr) ldsd[COLB + 8*r + rr] = acc[rr][0];
    }
    __syncthreads();
    for (int k = 0; k < NN; ++k) {
      const int pb = (k & 1) << 7;
      const int krt = k >> 3, kcl = k & 7;
      double rowk[8], colv[8];
#pragma unroll
      for (int cc = 0; cc < 8; ++cc) rowk[cc] = ldsd[ROWB + pb + 8*c + cc];
#pragma unroll
      for (int rr = 0; rr < 8; ++rr) colv[rr] = ldsd[COLB + pb + 8*r + rr];
      const double dkk  = ldsd[ROWB + pb + k];     // same-address broadcast
      const double rcpd = 1.0 / dkk;               // pivots >= 1 (M >= I)
      double rdv[8];
#pragma unroll
      for (int cc = 0; cc < 8; ++cc) rdv[cc] = rowk[cc] * rcpd;
      const bool pivR = (r == krt), pivC = (c == krt);
#pragma unroll
      for (int rr = 0; rr < 8; ++rr) {
        const double cv = colv[rr] * rcpd;
        const bool pr = pivR && (rr == kcl);
#pragma unroll
        for (int cc = 0; cc < 8; ++cc) {
          double gen = fma(-cv, rowk[cc], acc[rr][cc]);
          acc[rr][cc] = pr ? rdv[cc] : gen;
        }
      }
      if (pivC) {
#pragma unroll
        for (int cc = 0; cc < 8; ++cc) if (cc == kcl) {
#pragma unroll
          for (int rr = 0; rr < 8; ++rr) {
            const bool pr2 = pivR && (rr == kcl);
            acc[rr][cc] = pr2 ? -rcpd : colv[rr] * rcpd;
          }
        }
      }
      if (k < NN - 1) {
        const int pb2 = ((k + 1) & 1) << 7;
        const int krt2 = (k + 1) >> 3, kcl2 = (k + 1) & 7;
        if (r == krt2) {
#pragma unroll
          for (int rr = 0; rr < 8; ++rr) if (rr == kcl2) {
#pragma unroll
            for (int cc = 0; cc < 8; ++cc) ldsd[ROWB + pb2 + 8*c + cc] = acc[rr][cc];
          }
        }
        if (c == krt2) {
#pragma unroll
          for (int cc = 0; cc < 8; ++cc) if (cc == kcl2) {
#pragma unroll
            for (int rr = 0; rr < 8; ++rr) ldsd[COLB + pb2 + 8*r + rr] = acc[rr][cc];
          }
        }
      }
      __syncthreads();
    }
#pragma unroll
    for (int rr = 0; rr < 8; ++rr) {
      double2* dst = (double2*)(ldsd + (8*r+rr)*ROWD + 8*c);
#pragma unroll
      for (int t = 0; t < 4; ++t) dst[t] = make_double2(acc[rr][2*t], acc[rr][2*t+1]);
    }
  }
  __syncthreads();

  // ---------------- Stage 2: K = B (R B^T) in 8 blocks of 12 cols --------
  // NEW ownership: w0 holds cols 0..47 (blks 0-3), w1 holds cols 48..95 (blks 4-7),
  // each as 24 f32x2 pairs. Waves 2,3 hold nothing.
  f32x2 Kp[24], Kp2[24];
  for (int blk = 0; blk < 8; ++blk) {
    {
      const float* gp[6];
#pragma unroll
      for (int jj = 0; jj < 6; ++jj) {
        int it = 12*blk + 6*hh + jj;
        gp[jj] = (it < DI) ? (Gb + it*NN) : (Ab + (it - DI)*NN);
      }
      double a2[6] = {0,0,0,0,0,0};
#pragma unroll 4
      for (int t = 0; t < NN; ++t) {
        double rv = ldsd[t*ROWD + ia];
#pragma unroll
        for (int jj = 0; jj < 6; ++jj)
          a2[jj] = fma(rv, (double)gp[jj][t], a2[jj]);
      }
      double2* yst = (double2*)(ldsd + YBUF + ia*12 + 6*hh);
#pragma unroll
      for (int p = 0; p < 3; ++p) yst[p] = make_double2(a2[2*p], a2[2*p+1]);
    }
    __syncthreads();
    {
      const int r2 = (ia < NZ) ? ia : 0;
      const float* brow = (r2 < DI) ? (Gb + r2*NN) : (Ab + (r2 - DI)*NN);
      double a2[6] = {0,0,0,0,0,0};
#pragma unroll 4
      for (int t = 0; t < NN; ++t) {
        double bvv = (double)brow[t];
        const double2* yr = (const double2*)(ldsd + YBUF + t*12 + 6*hh);
        double2 y0 = yr[0], y1 = yr[1], y2 = yr[2];
        a2[0] = fma(bvv, y0.x, a2[0]); a2[1] = fma(bvv, y0.y, a2[1]);
        a2[2] = fma(bvv, y1.x, a2[2]); a2[3] = fma(bvv, y1.y, a2[3]);
        a2[4] = fma(bvv, y2.x, a2[4]); a2[5] = fma(bvv, y2.y, a2[5]);
      }
      if (ia < NZ) {
#pragma unroll
        for (int jj = 0; jj < 6; ++jj) ldsd[KBUF + (6*hh + jj)*NZ + ia] = a2[jj];
      }
    }
    __syncthreads();
    if (w == 0) {
      if (blk == 0)      { CPY12(0) }
      else if (blk == 1) { CPY12(6) }
      else if (blk == 2) { CPY12(12) }
      else if (blk == 3) { CPY12(18) }
    } else if (w == 1) {
      if (blk == 4)      { CPY12(0) }
      else if (blk == 5) { CPY12(6) }
      else if (blk == 6) { CPY12(12) }
      else if (blk == 7) { CPY12(18) }
    }
    __syncthreads();
  }

  // ---------------- Stage 3a: c = q - G^T h - A^T b ----------------
  {
    double s = 0;
#pragma unroll 8
    for (int jc = 0; jc < 48; ++jc) {
      int j = 48*hh + jc;
      double coef = (j < DI) ? ldsd[HB + j] : ldsd[BB + j - DI];
      const float* src = (j < DI) ? (Gb + j*NN) : (Ab + (j - DI)*NN);
      s = fma(-(double)src[ia], coef, s);
    }
    ldsd[CPART + hh*128 + ia] = s;
  }
  __syncthreads();
  if (tid < NN) ldsd[CB + tid] = ldsd[QBUF + tid] + ldsd[CPART + tid] + ldsd[CPART + 128 + tid];
  __syncthreads();

  // ---------------- Stage 3b: v1 = R c, v2 = R q ----------------
  {
    double a = 0, b2 = 0;
#pragma unroll 4
    for (int tt = 0; tt < 64; ++tt) {
      int t = 64*hh + tt;
      double rv = ldsd[t*ROWD + ia];
      a  = fma(rv, ldsd[CB + t], a);
      b2 = fma(rv, ldsd[QBUF + t], b2);
    }
    ldsd[VP + hh*128 + ia] = a;
    ldsd[VP + 256 + hh*128 + ia] = b2;
  }
  __syncthreads();
  if (tid < NN) {
    ldsd[V1 + tid] = ldsd[VP + tid] + ldsd[VP + 128 + tid];
    ldsd[V2 + tid] = ldsd[VP + 256 + tid] + ldsd[VP + 384 + tid];
  }
  __syncthreads();

  // ---------------- Stage 3c: base = B v1, qB = B v2, scalars ----------------
  {
    const int r2 = (ia < NZ) ? ia : 0;
    const float* brow = (r2 < DI) ? (Gb + r2*NN) : (Ab + (r2 - DI)*NN);
    const int voff = hh ? V2 : V1;
    double s = 0;
#pragma unroll 4
    for (int t = 0; t < NN; ++t) s = fma((double)brow[t], ldsd[voff + t], s);
    if (ia < NZ) ldsd[(hh ? QBV : BASEV) + ia] = s;
  }
  if (w == 0) {
    double pc = ldsd[V1+l]*ldsd[CB+l]   + ldsd[V1+64+l]*ldsd[CB+64+l];
    double pq = ldsd[V1+l]*ldsd[QBUF+l] + ldsd[V1+64+l]*ldsd[QBUF+64+l];
#pragma unroll
    for (int off = 32; off >= 1; off >>= 1) { pc += __shfl_xor(pc, off); pq += __shfl_xor(pq, off); }
    if (l == 0) { ldsd[CST] = pc; ldsd[CST+1] = pq; }
  }
  __syncthreads();

  // ---------------- Loop setup ----------------
  // w0: matvec cols 0..47 (all z_lo) + lo-ring + z_lo publish.
  // w1: matvec cols 48..95 (z_lo 48-63 + z_hi 0-31) + hi-ring + z_hi publish.
  // w2: tv + stage A (obj pipeline front; one serial f64 chain).
  // w3: stage B + flag (obj pipeline back; the other serial chain).
  // Exchange: 2 packed b64 slots; own partial stays in registers (1 remote read).
  const double baseA = ldsd[BASEV + l];
  const double baseB = ldsd[BASEV + 64 + lm];
  const double qvA   = ldsd[QBV + l];
  const double qvB   = ldsd[QBV + 64 + lm];
  const double hb2   = ldsd[HB + l] - baseA;       // h - baseA
  const double bb2   = baseB - ldsd[BB + lm];      // baseB - b
  const double S_uc  = ldsd[CST], S_qu = ldsd[CST + 1];
  double hnb = hb2, lb = bb2;                      // nu = 0, lam = 0 folded
  double zlo = 0.0, zhi = 0.0;
  double zAlo = 0.0, zAhi = 0.0, zBlo = 0.0, zBhi = 0.0, zClo = 0.0, zChi = 0.0;
  double res_prev = 1000.0, res_cur = -100.0;      // w3 obj recurrence
  float2 own = make_float2(0.f, 0.f);              // own partial (w0/w1), reg-resident

  // prologue: zero P buf0 slots; z(-1)=0 into ZEX buf1; flags 0
  {
    if (w < 2) *(float2*)&ldsd[PPK + w*64 + l] = make_float2(0.f, 0.f);
    if (w == 0) ldsd[ZEXL + 64 + l] = 0.0;
    if (w == 1 && l < 32) ldsd[ZEXH + 32 + l] = 0.0;
    if (tid == 0) { ldsd[FLG] = 0.0; ldsd[FLG + 1] = 0.0; }
  }

  // ---------------- ADMM loop: 1 barrier/body ----------------
  for (int it = 0; it < MAXIT + 3; ++it) {
    __syncthreads();
    const int buf = it & 1, nbuf = buf ^ 1;
    const int bprev = nbuf;                 // (it-1)&1
    const double fl = ldsd[FLG + bprev];    // flag stored body it-1 = decision for obj_{it-3}

    if (w < 2) {
      // ONE remote b64 read; own partial from registers
      float2 rem = *(const float2*)&ldsd[PPK + buf*128 + (w ^ 1)*64 + l];
      float slo = own.x + rem.x;
      double t = hnb - (double)slo;
      float zflo = (float)fabs(t);
      float zfhi = 0.f;
      double lamn = 0.0;
      if (w == 1) {
        float shi = own.y + rem.y;
        lamn = lb + (double)shi;
        zfhi = (float)lamn;
      }
      if (it >= 3 && fl != 0.0) break;
      // ring shifts (zA = z entering THIS body)
      if (w == 0) { zClo = zBlo; zBlo = zAlo; zAlo = zlo; }
      else        { zChi = zBhi; zBhi = zAhi; zAhi = zhi; }
      if (it < MAXIT) {
        if (w == 0) { zlo = fabs(t); ldsd[ZEXL + buf*64 + l] = zlo; }
        hnb = hb2 + fmin(t, 0.0);            // = hb2 - relu(-t); same in w0,w1
        if (w == 1) {
          zhi = lamn; lb = lamn + bb2;
          if (l < 32) ldsd[ZEXH + buf*32 + l] = lamn;
        }
        // matvec burst: 48 cols per wave
        f32x2 A0 = {0.f, 0.f}, A1 = A0, B0 = A0, B1 = A0;
        if (w == 0) {
          MV2(0,  zflo, 0)  MV2(2,  zflo, 4)  MV2(4,  zflo, 8)  MV2(6,  zflo, 12)
          MV2(8,  zflo, 16) MV2(10, zflo, 20) MV2(12, zflo, 24) MV2(14, zflo, 28)
          MV2(16, zflo, 32) MV2(18, zflo, 36) MV2(20, zflo, 40) MV2(22, zflo, 44)
        } else {
          MV2(0,  zflo, 48) MV2(2,  zflo, 52) MV2(4,  zflo, 56) MV2(6,  zflo, 60)
          MV2(8,  zfhi, 0)  MV2(10, zfhi, 4)  MV2(12, zfhi, 8)  MV2(14, zfhi, 12)
          MV2(16, zfhi, 16) MV2(18, zfhi, 20) MV2(20, zfhi, 24) MV2(22, zfhi, 28)
        }
        f32x2 As = A0 + A1, Bs = B0 + B1;     // v_pk_add_f32
        float2 np = make_float2(As.x + As.y, Bs.x + Bs.y);
        *(float2*)&ldsd[PPK + nbuf*128 + w*64 + l] = np;
        own = np;
      }
    } else if (w == 2) {
      // ---------------- obj front: tv (pipeline it) + stage A (it-1) ----------------
      const float2* pb = (const float2*)(ldsd + PPK + buf*128);
      float2 v0 = pb[l], v1 = pb[64 + l];
      const double zAl = ldsd[ZEXL + bprev*64 + l];    // z_top(it) = z(it-1)
      const double zAh = ldsd[ZEXH + bprev*32 + lm];
      const int g = l & 15;
      const double* tq = ldsd + TVX + bprev*64;        // tv(it-1), stride-16 quartet
      double a0 = tq[g], a1 = tq[g + 16], a2 = tq[g + 32], a3 = tq[g + 48];
      if (it >= 3 && fl != 0.0) break;
      if (it < MAXIT) {
        float slo_f = v0.x + v1.x;
        float shi_f = v0.y + v1.y;
        double yf  = (double)slo_f + baseA;
        double tvl = fma(qvA, zAl, -0.5*(zAl*(baseA + yf) + yf*yf));
        double yfB = (double)shi_f + baseB;
        double tvh = fma(qvB, zAh, -0.5*(zAh*(baseB + yfB) + yfB*yfB));
        ldsd[TVX + buf*64 + l] = tvl + ((l < 32) ? tvh : 0.0);
      }
      if (l < 16 && it >= 1 && it <= MAXIT)
        ldsd[TV16 + buf*16 + l] = (a0 + a1) + (a2 + a3);
    } else {
      // ---------------- obj back: stage B (pipeline it-2) -> flag ----------------
      double t1v[16];
      const double2* tp = (const double2*)(ldsd + TV16 + bprev*16);  // sums of tv(it-2)
#pragma unroll
      for (int u = 0; u < 8; ++u) { double2 vv = tp[u]; t1v[2*u] = vv.x; t1v[2*u+1] = vv.y; }
      if (it >= 3 && fl != 0.0) break;
      if (it >= 2 && it <= MAXIT + 1) {
        double s1 = ((t1v[0] + t1v[1]) + (t1v[2] + t1v[3])) + ((t1v[4] + t1v[5]) + (t1v[6] + t1v[7]));
        double s2 = ((t1v[8] + t1v[9]) + (t1v[10] + t1v[11])) + ((t1v[12] + t1v[13]) + (t1v[14] + t1v[15]));
        double obj = (s1 + s2) - 0.5*S_uc + S_qu;
        res_prev = res_cur; res_cur = obj;
        if (l == 0)
          ldsd[FLG + buf] = (fabs(res_cur - res_prev) <= 1e-5 * fabs(res_prev)) ? 1.0 : 0.0;
      }
    }
  }

  // ---------------- Final: publish z (rings: zC = top-of-stopping-body) -> LDS ------
  if (w == 0) ldsd[ZBF + l] = zClo;
  if (w == 1 && l < 32) ldsd[ZBF + 64 + l] = zChi;
  __syncthreads();
  // x = R (c + B^T z); z read via broadcast LDS loads
  {
    double s = 0;
#pragma unroll 8
    for (int jc = 0; jc < 48; ++jc) {
      int j = 48*hh + jc;
      double zj = ldsd[ZBF + j];
      const float* src = (j < DI) ? (Gb + j*NN) : (Ab + (j - DI)*NN);
      s = fma((double)src[ia], zj, s);
    }
    ldsd[FPART + hh*128 + ia] = s;
  }
  __syncthreads();
  if (tid < NN) ldsd[RHSV + tid] = ldsd[CB + tid] + ldsd[FPART + tid] + ldsd[FPART + 128 + tid];
  __syncthreads();
  {
    double s = 0;
#pragma unroll 4
    for (int tt = 0; tt < 64; ++tt) {
      int t = 64*hh + tt;
      s = fma(ldsd[t*ROWD + ia], ldsd[RHSV + t], s);   // R[t][ia] = R[ia][t]
    }
    ldsd[XPART + hh*128 + ia] = s;
  }
  __syncthreads();
  if (tid < NN)
    out[(size_t)bidx * NN + tid] = (float)(ldsd[XPART + tid] + ldsd[XPART + 128 + tid]);
}

extern "C" void kernel_launch(void* const* d_in, const int* in_sizes, int n_in,
                              void* d_out, int out_size, void* d_ws, size_t ws_size,
                              hipStream_t stream) {
  (void)in_sizes; (void)n_in; (void)out_size; (void)d_ws; (void)ws_size;
  const float* Q = (const float*)d_in[0];
  const float* q = (const float*)d_in[1];
  const float* G = (const float*)d_in[2];
  const float* h = (const float*)d_in[3];
  const float* A = (const float*)d_in[4];
  const float* b = (const float*)d_in[5];
  float* out = (float*)d_out;
  const size_t lds_bytes = (size_t)LDS_DBL * sizeof(double);  // 160320
  altdiff_kernel<<<dim3(64), dim3(256), lds_bytes, stream>>>(Q, q, G, h, A, b, out);
}

// Round 5
// 597.459 us; speedup vs baseline: 1.1832x; 1.0561x over previous
//
#include <hip/hip_runtime.h>

#define NN 128
#define ME 32
#define DI 64
#define NZ 96
#define ROWD 130
#define MAXIT 5000

// ---- LDS layout (double offsets). R: [0, 16640). Total 20040 dbl = 160320 B <= 163840.
#define OFF_UN 16640
#define ROWB  (OFF_UN)           // [2][128] sweep row-k buffer (phase 2)
#define COLB  (OFF_UN + 256)     // [2][128] sweep col-k buffer (phase 2)
// loop window (3-slot exchange + dedicated obj wave):
#define PPK   (OFF_UN)           // [2][3][64] packed (lo,hi) f32 partials in b64 slots
#define ZEXL  (OFF_UN + 384)     // [2][64] f64 z_lo publish (w0 -> w3 tv)
#define ZEXH  (OFF_UN + 512)     // [2][32] f64 z_hi publish (w2 -> w3 tv)
#define TVX   (OFF_UN + 576)     // [2][64] f64 per-lane tv terms (w3 internal)
#define TV16  (OFF_UN + 704)     // [2][16] f64 stage-A sums (w3 internal)
#define FLG   (OFF_UN + 736)     // [2] convergence flag (double 0/1)
#define YBUF  (OFF_UN)           // [128][12] Y block (stage 2; dead before loop)
#define KBUF  (OFF_UN + 1536)    // [12][96] K cols (stage 2; dead before loop)
#define CPART (OFF_UN + 1024)    // [2][128] (stage 3a)
#define VP    (OFF_UN + 1280)    // [4][128] (stage 3b)
#define BASEV (OFF_UN + 1792)    // [96] (persists through loop)
#define QBV   (OFF_UN + 1888)    // [96] (persists through loop)
#define FPART (OFF_UN + 1024)    // [2][128] (final)
#define RHSV  (OFF_UN + 1280)    // [128] (final)
#define XPART (OFF_UN + 1408)    // [2][128] (final)
#define CB    (OFF_UN + 2688)    // [128] c
#define QBUF  (OFF_UN + 2816)    // [128] q
#define V1    (OFF_UN + 2944)    // [128] Rc
#define V2    (OFF_UN + 3072)    // [128] Rq
#define HB    (OFF_UN + 3200)    // [64]
#define BB    (OFF_UN + 3264)    // [32]
#define CST   (OFF_UN + 3296)    // [8]: 0=u.c 1=q.u
#define ZBF   (OFF_UN + 3304)    // [96] z publish (final)
#define LDS_DBL (OFF_UN + 3400)  // 20040

typedef __attribute__((ext_vector_type(2))) float f32x2;

// f32 SGPR broadcast. CONTRACT: source computed by all lanes of the wave.
__device__ __forceinline__ float rlf(float v, int lane) {
  return __uint_as_float((unsigned)__builtin_amdgcn_readlane((int)__float_as_uint(v), lane));
}
__device__ __forceinline__ f32x2 fma2(f32x2 a, f32x2 b, f32x2 c) {
  return __builtin_elementwise_fma(a, b, c);   // v_pk_fma_f32
}

// matvec step: 2 pairs (4 cols) with broadcast lanes L0..L0+3 of ZS
#define MV2(PA, ZS, L0) {                                                  \
    f32x2 z0 = { rlf(ZS, L0), rlf(ZS, (L0)+1) };                           \
    A0 = fma2(Kp[PA], z0, A0); B0 = fma2(Kp2[PA], z0, B0);                 \
    f32x2 z1 = { rlf(ZS, (L0)+2), rlf(ZS, (L0)+3) };                       \
    A1 = fma2(Kp[(PA)+1], z1, A1); B1 = fma2(Kp2[(PA)+1], z1, B1); }

// copy KBUF cols [KBASE, KBASE+CNT) into local K pairs starting at local col LBASE
#define CPYRANGE(LBASE, KBASE, CNT)                                        \
  _Pragma("unroll") for (int j = 0; j < (CNT); ++j) {                      \
    const int lj = (LBASE) + j, kc = (KBASE) + j;                          \
    float va = (float)ldsd[KBUF + kc*NZ + l];                              \
    float vb = (float)ldsd[KBUF + kc*NZ + 64 + lm];                        \
    if ((lj & 1) == 0) { Kp[lj>>1].x = va; Kp2[lj>>1].x = vb; }            \
    else               { Kp[lj>>1].y = va; Kp2[lj>>1].y = vb; }            \
  }

__global__ __launch_bounds__(256, 1) void altdiff_kernel(
    const float* __restrict__ Qg, const float* __restrict__ qg,
    const float* __restrict__ Gg, const float* __restrict__ hg,
    const float* __restrict__ Ag, const float* __restrict__ bg,
    float* __restrict__ out)
{
  extern __shared__ double ldsd[];

  const int bidx = blockIdx.x;
  const int tid  = threadIdx.x;
  const int w    = tid >> 6;     // wave 0..3
  const int l    = tid & 63;     // lane
  const int lm   = l & 31;
  const int ia   = tid & 127;    // 128-split index
  const int hh   = tid >> 7;     // 0..1 (wave-uniform)

  const float* Qb = Qg + (size_t)bidx * NN * NN;
  const float* Ab = Ag + (size_t)bidx * ME * NN;
  const float* Gb = Gg + (size_t)bidx * DI * NN;
  const float* qb = qg + (size_t)bidx * NN;
  const float* hb = hg + (size_t)bidx * DI;
  const float* bv = bg + (size_t)bidx * ME;

  // stage h, b, q (f64)
  if (tid < DI) ldsd[HB + tid] = (double)hb[tid];
  else if (tid < DI + ME) ldsd[BB + tid - DI] = (double)bv[tid - DI];
  if (tid >= 128) ldsd[QBUF + tid - 128] = (double)qb[tid - 128];

  const int r = tid >> 4, c = tid & 15;   // 8x8 register tile at rows 8r.., cols 8c..
  double acc[8][8];                       // ALL indices compile-time constant (no scratch)

  // ---------------- Phase 1: M = Q + A^T A + G^T G (f64) -> registers ----------------
  {
    const float4* Q4 = (const float4*)Qb;
#pragma unroll
    for (int rr = 0; rr < 8; ++rr) {
      float4 q0 = Q4[((8*r+rr) << 5) + 2*c];
      float4 q1 = Q4[((8*r+rr) << 5) + 2*c + 1];
      acc[rr][0]=(double)q0.x; acc[rr][1]=(double)q0.y; acc[rr][2]=(double)q0.z; acc[rr][3]=(double)q0.w;
      acc[rr][4]=(double)q1.x; acc[rr][5]=(double)q1.y; acc[rr][6]=(double)q1.z; acc[rr][7]=(double)q1.w;
    }
    const float4* A4 = (const float4*)Ab;
    for (int m = 0; m < ME; ++m) {
      float4 u0 = A4[(m << 5) + 2*r], u1 = A4[(m << 5) + 2*r + 1];
      float4 v0 = A4[(m << 5) + 2*c], v1 = A4[(m << 5) + 2*c + 1];
      double uu[8] = {(double)u0.x,(double)u0.y,(double)u0.z,(double)u0.w,
                      (double)u1.x,(double)u1.y,(double)u1.z,(double)u1.w};
      double vv[8] = {(double)v0.x,(double)v0.y,(double)v0.z,(double)v0.w,
                      (double)v1.x,(double)v1.y,(double)v1.z,(double)v1.w};
#pragma unroll
      for (int rr = 0; rr < 8; ++rr)
#pragma unroll
        for (int cc = 0; cc < 8; ++cc)
          acc[rr][cc] = fma(uu[rr], vv[cc], acc[rr][cc]);
    }
    const float4* G4 = (const float4*)Gb;
    for (int d = 0; d < DI; ++d) {
      float4 u0 = G4[(d << 5) + 2*r], u1 = G4[(d << 5) + 2*r + 1];
      float4 v0 = G4[(d << 5) + 2*c], v1 = G4[(d << 5) + 2*c + 1];
      double uu[8] = {(double)u0.x,(double)u0.y,(double)u0.z,(double)u0.w,
                      (double)u1.x,(double)u1.y,(double)u1.z,(double)u1.w};
      double vv[8] = {(double)v0.x,(double)v0.y,(double)v0.z,(double)v0.w,
                      (double)v1.x,(double)v1.y,(double)v1.z,(double)v1.w};
#pragma unroll
      for (int rr = 0; rr < 8; ++rr)
#pragma unroll
        for (int cc = 0; cc < 8; ++cc)
          acc[rr][cc] = fma(uu[rr], vv[cc], acc[rr][cc]);
    }
  }

  // ---------------- Phase 2: register-tile sweep, 1 barrier/pivot, double-buffered ----------
  {
    if (r == 0) {
#pragma unroll
      for (int cc = 0; cc < 8; ++cc) ldsd[ROWB + 8*c + cc] = acc[0][cc];
    }
    if (c == 0) {
#pragma unroll
      for (int rr = 0; rr < 8; ++rr) ldsd[COLB + 8*r + rr] = acc[rr][0];
    }
    __syncthreads();
    for (int k = 0; k < NN; ++k) {
      const int pb = (k & 1) << 7;
      const int krt = k >> 3, kcl = k & 7;
      double rowk[8], colv[8];
#pragma unroll
      for (int cc = 0; cc < 8; ++cc) rowk[cc] = ldsd[ROWB + pb + 8*c + cc];
#pragma unroll
      for (int rr = 0; rr < 8; ++rr) colv[rr] = ldsd[COLB + pb + 8*r + rr];
      const double dkk  = ldsd[ROWB + pb + k];     // same-address broadcast
      const double rcpd = 1.0 / dkk;               // pivots >= 1 (M >= I)
      double rdv[8];
#pragma unroll
      for (int cc = 0; cc < 8; ++cc) rdv[cc] = rowk[cc] * rcpd;
      const bool pivR = (r == krt), pivC = (c == krt);
#pragma unroll
      for (int rr = 0; rr < 8; ++rr) {
        const double cv = colv[rr] * rcpd;
        const bool pr = pivR && (rr == kcl);
#pragma unroll
        for (int cc = 0; cc < 8; ++cc) {
          double gen = fma(-cv, rowk[cc], acc[rr][cc]);
          acc[rr][cc] = pr ? rdv[cc] : gen;
        }
      }
      if (pivC) {
#pragma unroll
        for (int cc = 0; cc < 8; ++cc) if (cc == kcl) {
#pragma unroll
          for (int rr = 0; rr < 8; ++rr) {
            const bool pr2 = pivR && (rr == kcl);
            acc[rr][cc] = pr2 ? -rcpd : colv[rr] * rcpd;
          }
        }
      }
      if (k < NN - 1) {
        const int pb2 = ((k + 1) & 1) << 7;
        const int krt2 = (k + 1) >> 3, kcl2 = (k + 1) & 7;
        if (r == krt2) {
#pragma unroll
          for (int rr = 0; rr < 8; ++rr) if (rr == kcl2) {
#pragma unroll
            for (int cc = 0; cc < 8; ++cc) ldsd[ROWB + pb2 + 8*c + cc] = acc[rr][cc];
          }
        }
        if (c == krt2) {
#pragma unroll
          for (int cc = 0; cc < 8; ++cc) if (cc == kcl2) {
#pragma unroll
            for (int rr = 0; rr < 8; ++rr) ldsd[COLB + pb2 + 8*r + rr] = acc[rr][cc];
          }
        }
      }
      __syncthreads();
    }
#pragma unroll
    for (int rr = 0; rr < 8; ++rr) {
      double2* dst = (double2*)(ldsd + (8*r+rr)*ROWD + 8*c);
#pragma unroll
      for (int t = 0; t < 4; ++t) dst[t] = make_double2(acc[rr][2*t], acc[rr][2*t+1]);
    }
  }
  __syncthreads();

  // ---------------- Stage 2: K = B (R B^T) in 8 blocks of 12 cols --------
  // Ownership: w0 cols 0..31, w1 cols 32..63, w2 cols 64..95 (16 f32x2 pairs each).
  // Wave 3 holds nothing (objective wave).
  f32x2 Kp[16], Kp2[16];
  for (int blk = 0; blk < 8; ++blk) {
    {
      const float* gp[6];
#pragma unroll
      for (int jj = 0; jj < 6; ++jj) {
        int it = 12*blk + 6*hh + jj;
        gp[jj] = (it < DI) ? (Gb + it*NN) : (Ab + (it - DI)*NN);
      }
      double a2[6] = {0,0,0,0,0,0};
#pragma unroll 4
      for (int t = 0; t < NN; ++t) {
        double rv = ldsd[t*ROWD + ia];
#pragma unroll
        for (int jj = 0; jj < 6; ++jj)
          a2[jj] = fma(rv, (double)gp[jj][t], a2[jj]);
      }
      double2* yst = (double2*)(ldsd + YBUF + ia*12 + 6*hh);
#pragma unroll
      for (int p = 0; p < 3; ++p) yst[p] = make_double2(a2[2*p], a2[2*p+1]);
    }
    __syncthreads();
    {
      const int r2 = (ia < NZ) ? ia : 0;
      const float* brow = (r2 < DI) ? (Gb + r2*NN) : (Ab + (r2 - DI)*NN);
      double a2[6] = {0,0,0,0,0,0};
#pragma unroll 4
      for (int t = 0; t < NN; ++t) {
        double bvv = (double)brow[t];
        const double2* yr = (const double2*)(ldsd + YBUF + t*12 + 6*hh);
        double2 y0 = yr[0], y1 = yr[1], y2 = yr[2];
        a2[0] = fma(bvv, y0.x, a2[0]); a2[1] = fma(bvv, y0.y, a2[1]);
        a2[2] = fma(bvv, y1.x, a2[2]); a2[3] = fma(bvv, y1.y, a2[3]);
        a2[4] = fma(bvv, y2.x, a2[4]); a2[5] = fma(bvv, y2.y, a2[5]);
      }
      if (ia < NZ) {
#pragma unroll
        for (int jj = 0; jj < 6; ++jj) ldsd[KBUF + (6*hh + jj)*NZ + ia] = a2[jj];
      }
    }
    __syncthreads();
    // copy-out: constant indices per (wave, blk) arm
    if (w == 0) {
      if (blk == 0)      { CPYRANGE(0,  0, 12) }
      else if (blk == 1) { CPYRANGE(12, 0, 12) }
      else if (blk == 2) { CPYRANGE(24, 0, 8) }
    } else if (w == 1) {
      if (blk == 2)      { CPYRANGE(0,  8, 4) }
      else if (blk == 3) { CPYRANGE(4,  0, 12) }
      else if (blk == 4) { CPYRANGE(16, 0, 12) }
      else if (blk == 5) { CPYRANGE(28, 0, 4) }
    } else if (w == 2) {
      if (blk == 5)      { CPYRANGE(0,  4, 8) }
      else if (blk == 6) { CPYRANGE(8,  0, 12) }
      else if (blk == 7) { CPYRANGE(20, 0, 12) }
    }
    __syncthreads();
  }

  // ---------------- Stage 3a: c = q - G^T h - A^T b ----------------
  {
    double s = 0;
#pragma unroll 8
    for (int jc = 0; jc < 48; ++jc) {
      int j = 48*hh + jc;
      double coef = (j < DI) ? ldsd[HB + j] : ldsd[BB + j - DI];
      const float* src = (j < DI) ? (Gb + j*NN) : (Ab + (j - DI)*NN);
      s = fma(-(double)src[ia], coef, s);
    }
    ldsd[CPART + hh*128 + ia] = s;
  }
  __syncthreads();
  if (tid < NN) ldsd[CB + tid] = ldsd[QBUF + tid] + ldsd[CPART + tid] + ldsd[CPART + 128 + tid];
  __syncthreads();

  // ---------------- Stage 3b: v1 = R c, v2 = R q ----------------
  {
    double a = 0, b2 = 0;
#pragma unroll 4
    for (int tt = 0; tt < 64; ++tt) {
      int t = 64*hh + tt;
      double rv = ldsd[t*ROWD + ia];
      a  = fma(rv, ldsd[CB + t], a);
      b2 = fma(rv, ldsd[QBUF + t], b2);
    }
    ldsd[VP + hh*128 + ia] = a;
    ldsd[VP + 256 + hh*128 + ia] = b2;
  }
  __syncthreads();
  if (tid < NN) {
    ldsd[V1 + tid] = ldsd[VP + tid] + ldsd[VP + 128 + tid];
    ldsd[V2 + tid] = ldsd[VP + 256 + tid] + ldsd[VP + 384 + tid];
  }
  __syncthreads();

  // ---------------- Stage 3c: base = B v1, qB = B v2, scalars ----------------
  {
    const int r2 = (ia < NZ) ? ia : 0;
    const float* brow = (r2 < DI) ? (Gb + r2*NN) : (Ab + (r2 - DI)*NN);
    const int voff = hh ? V2 : V1;
    double s = 0;
#pragma unroll 4
    for (int t = 0; t < NN; ++t) s = fma((double)brow[t], ldsd[voff + t], s);
    if (ia < NZ) ldsd[(hh ? QBV : BASEV) + ia] = s;
  }
  if (w == 0) {
    double pc = ldsd[V1+l]*ldsd[CB+l]   + ldsd[V1+64+l]*ldsd[CB+64+l];
    double pq = ldsd[V1+l]*ldsd[QBUF+l] + ldsd[V1+64+l]*ldsd[QBUF+64+l];
#pragma unroll
    for (int off = 32; off >= 1; off >>= 1) { pc += __shfl_xor(pc, off); pq += __shfl_xor(pq, off); }
    if (l == 0) { ldsd[CST] = pc; ldsd[CST+1] = pq; }
  }
  __syncthreads();

  // ---------------- Loop setup ----------------
  // w0: cols 0..31 (z_lo lanes 0-31) + lo chain + lo ring + ZEXL publish.
  // w1: cols 32..63 (z_lo lanes 32-63) + lo chain (duplicate state, bit-identical).
  // w2: cols 64..95 (z_hi lanes 0-31) + hi chain + hi ring + ZEXH publish.
  // w3: objective pipeline (tv -> stage A -> stage B -> flag), r3/r4 timing verbatim.
  // Exchange: 3 packed b64 slots; own partial reg-resident; 2 remote reads (parallel).
  // All waves sum slots in the SAME order (s0+s1)+s2 so duplicated state matches.
  const double baseA = ldsd[BASEV + l];
  const double baseB = ldsd[BASEV + 64 + lm];
  const double qvA   = ldsd[QBV + l];
  const double qvB   = ldsd[QBV + 64 + lm];
  const double hb2   = ldsd[HB + l] - baseA;       // h - baseA
  const double bb2   = baseB - ldsd[BB + lm];      // baseB - b
  const double S_uc  = ldsd[CST], S_qu = ldsd[CST + 1];
  double hnb = hb2, lb = bb2;                      // nu = 0, lam = 0 folded
  double zlo = 0.0, zhi = 0.0;
  double zAlo = 0.0, zAhi = 0.0, zBlo = 0.0, zBhi = 0.0, zClo = 0.0, zChi = 0.0;
  double res_prev = 1000.0, res_cur = -100.0;      // w3 obj recurrence
  float2 own = make_float2(0.f, 0.f);              // own partial (w0/w1/w2), reg-resident

  // prologue: zero P buf0 slots; z(-1)=0 into ZEX buf1; flags 0
  {
    if (w < 3) *(float2*)&ldsd[PPK + w*64 + l] = make_float2(0.f, 0.f);
    if (w == 0) ldsd[ZEXL + 64 + l] = 0.0;
    if (w == 2 && l < 32) ldsd[ZEXH + 32 + l] = 0.0;
    if (tid == 0) { ldsd[FLG] = 0.0; ldsd[FLG + 1] = 0.0; }
  }

  // ---------------- ADMM loop: 1 barrier/body ----------------
  for (int it = 0; it < MAXIT + 3; ++it) {
    __syncthreads();
    const int buf = it & 1, nbuf = buf ^ 1;
    const int bprev = nbuf;                 // (it-1)&1
    const double fl = ldsd[FLG + bprev];    // flag stored body it-1 = decision for obj_{it-3}
    const float2* pb = (const float2*)(ldsd + PPK + buf*192);

    if (w == 0) {
      float2 s1v = pb[64 + l], s2v = pb[128 + l];
      float slo = (own.x + s1v.x) + s2v.x;            // (s0+s1)+s2
      double t = hnb - (double)slo;
      float zflo = (float)fabs(t);
      if (it >= 3 && fl != 0.0) break;
      zClo = zBlo; zBlo = zAlo; zAlo = zlo;
      if (it < MAXIT) {
        zlo = fabs(t);
        ldsd[ZEXL + buf*64 + l] = zlo;
        hnb = hb2 + fmin(t, 0.0);                     // = hb2 - relu(-t)
        f32x2 A0 = {0.f, 0.f}, A1 = A0, B0 = A0, B1 = A0;
        MV2(0,  zflo, 0)  MV2(2,  zflo, 4)  MV2(4,  zflo, 8)  MV2(6,  zflo, 12)
        MV2(8,  zflo, 16) MV2(10, zflo, 20) MV2(12, zflo, 24) MV2(14, zflo, 28)
        f32x2 As = A0 + A1, Bs = B0 + B1;
        float2 np = make_float2(As.x + As.y, Bs.x + Bs.y);
        *(float2*)&ldsd[PPK + nbuf*192 + l] = np;
        own = np;
      }
    } else if (w == 1) {
      float2 s0v = pb[l], s2v = pb[128 + l];
      float slo = (s0v.x + own.x) + s2v.x;            // (s0+s1)+s2
      double t = hnb - (double)slo;
      float zflo = (float)fabs(t);
      if (it >= 3 && fl != 0.0) break;
      if (it < MAXIT) {
        hnb = hb2 + fmin(t, 0.0);
        f32x2 A0 = {0.f, 0.f}, A1 = A0, B0 = A0, B1 = A0;
        MV2(0,  zflo, 32) MV2(2,  zflo, 36) MV2(4,  zflo, 40) MV2(6,  zflo, 44)
        MV2(8,  zflo, 48) MV2(10, zflo, 52) MV2(12, zflo, 56) MV2(14, zflo, 60)
        f32x2 As = A0 + A1, Bs = B0 + B1;
        float2 np = make_float2(As.x + As.y, Bs.x + Bs.y);
        *(float2*)&ldsd[PPK + nbuf*192 + 64 + l] = np;
        own = np;
      }
    } else if (w == 2) {
      float2 s0v = pb[l], s1v = pb[64 + l];
      float shi = (s0v.y + s1v.y) + own.y;            // (s0+s1)+s2
      double lamn = lb + (double)shi;
      float zfhi = (float)lamn;
      if (it >= 3 && fl != 0.0) break;
      zChi = zBhi; zBhi = zAhi; zAhi = zhi;
      if (it < MAXIT) {
        zhi = lamn;
        lb = lamn + bb2;
        if (l < 32) ldsd[ZEXH + buf*32 + l] = lamn;
        f32x2 A0 = {0.f, 0.f}, A1 = A0, B0 = A0, B1 = A0;
        MV2(0,  zfhi, 0)  MV2(2,  zfhi, 4)  MV2(4,  zfhi, 8)  MV2(6,  zfhi, 12)
        MV2(8,  zfhi, 16) MV2(10, zfhi, 20) MV2(12, zfhi, 24) MV2(14, zfhi, 28)
        f32x2 As = A0 + A1, Bs = B0 + B1;
        float2 np = make_float2(As.x + As.y, Bs.x + Bs.y);
        *(float2*)&ldsd[PPK + nbuf*192 + 128 + l] = np;
        own = np;
      }
    } else {
      // ---------------- w3: objective pipeline ----------------
      float2 v0 = pb[l], v1 = pb[64 + l], v2 = pb[128 + l];
      const double zAl = ldsd[ZEXL + bprev*64 + l];    // z_top(it) = z(it-1)
      const double zAh = ldsd[ZEXH + bprev*32 + lm];
      const int g = l & 15;
      const double* tq = ldsd + TVX + bprev*64;        // tv(it-1), stride-16 quartet
      double a0 = tq[g], a1 = tq[g + 16], a2 = tq[g + 32], a3 = tq[g + 48];
      double t1v[16];
      const double2* tp = (const double2*)(ldsd + TV16 + bprev*16);  // sums of tv(it-2)
#pragma unroll
      for (int u = 0; u < 8; ++u) { double2 vv = tp[u]; t1v[2*u] = vv.x; t1v[2*u+1] = vv.y; }
      if (it >= 3 && fl != 0.0) break;
      // stage tv (pipeline it)
      if (it < MAXIT) {
        float slo_f = (v0.x + v1.x) + v2.x;
        float shi_f = (v0.y + v1.y) + v2.y;
        double yf  = (double)slo_f + baseA;
        double tvl = fma(qvA, zAl, -0.5*(zAl*(baseA + yf) + yf*yf));
        double yfB = (double)shi_f + baseB;
        double tvh = fma(qvB, zAh, -0.5*(zAh*(baseB + yfB) + yfB*yfB));
        ldsd[TVX + buf*64 + l] = tvl + ((l < 32) ? tvh : 0.0);
      }
      // stage A (pipeline it-1)
      if (l < 16 && it >= 1 && it <= MAXIT)
        ldsd[TV16 + buf*16 + l] = (a0 + a1) + (a2 + a3);
      // stage B (pipeline it-2) -> flag
      if (it >= 2 && it <= MAXIT + 1) {
        double s1 = ((t1v[0] + t1v[1]) + (t1v[2] + t1v[3])) + ((t1v[4] + t1v[5]) + (t1v[6] + t1v[7]));
        double s2 = ((t1v[8] + t1v[9]) + (t1v[10] + t1v[11])) + ((t1v[12] + t1v[13]) + (t1v[14] + t1v[15]));
        double obj = (s1 + s2) - 0.5*S_uc + S_qu;
        res_prev = res_cur; res_cur = obj;
        if (l == 0)
          ldsd[FLG + buf] = (fabs(res_cur - res_prev) <= 1e-5 * fabs(res_prev)) ? 1.0 : 0.0;
      }
    }
  }

  // ---------------- Final: publish z (rings: zC = top-of-stopping-body) -> LDS ------
  if (w == 0) ldsd[ZBF + l] = zClo;
  if (w == 2 && l < 32) ldsd[ZBF + 64 + l] = zChi;
  __syncthreads();
  // x = R (c + B^T z); z read via broadcast LDS loads
  {
    double s = 0;
#pragma unroll 8
    for (int jc = 0; jc < 48; ++jc) {
      int j = 48*hh + jc;
      double zj = ldsd[ZBF + j];
      const float* src = (j < DI) ? (Gb + j*NN) : (Ab + (j - DI)*NN);
      s = fma((double)src[ia], zj, s);
    }
    ldsd[FPART + hh*128 + ia] = s;
  }
  __syncthreads();
  if (tid < NN) ldsd[RHSV + tid] = ldsd[CB + tid] + ldsd[FPART + tid] + ldsd[FPART + 128 + tid];
  __syncthreads();
  {
    double s = 0;
#pragma unroll 4
    for (int tt = 0; tt < 64; ++tt) {
      int t = 64*hh + tt;
      s = fma(ldsd[t*ROWD + ia], ldsd[RHSV + t], s);   // R[t][ia] = R[ia][t]
    }
    ldsd[XPART + hh*128 + ia] = s;
  }
  __syncthreads();
  if (tid < NN)
    out[(size_t)bidx * NN + tid] = (float)(ldsd[XPART + tid] + ldsd[XPART + 128 + tid]);
}

extern "C" void kernel_launch(void* const* d_in, const int* in_sizes, int n_in,
                              void* d_out, int out_size, void* d_ws, size_t ws_size,
                              hipStream_t stream) {
  (void)in_sizes; (void)n_in; (void)out_size; (void)d_ws; (void)ws_size;
  const float* Q = (const float*)d_in[0];
  const float* q = (const float*)d_in[1];
  const float* G = (const float*)d_in[2];
  const float* h = (const float*)d_in[3];
  const float* A = (const float*)d_in[4];
  const float* b = (const float*)d_in[5];
  float* out = (float*)d_out;
  const size_t lds_bytes = (size_t)LDS_DBL * sizeof(double);  // 160320
  altdiff_kernel<<<dim3(64), dim3(256), lds_bytes, stream>>>(Q, q, G, h, A, b, out);
}